// Round 2
// baseline (846.727 us; speedup 1.0000x reference)
//
#include <hip/hip_runtime.h>
#include <cstdint>
#include <cstddef>

#define S_LEN 2048
#define EMB   1024
#define NH    16
#define DH    64

typedef unsigned short u16;
typedef __attribute__((ext_vector_type(8))) short bf16x8;   // 8 bf16 (4 VGPRs)
typedef __attribute__((ext_vector_type(4))) float f32x4;

__device__ __forceinline__ u16 f2bf(float f) {
  unsigned int u = __float_as_uint(f);
  u = (u + 0x7fffu + ((u >> 16) & 1u)) >> 16;   // RNE
  return (u16)u;
}

__device__ __forceinline__ void gload16(const void* g, void* l) {
  __builtin_amdgcn_global_load_lds(
      (const __attribute__((address_space(1))) unsigned int*)g,
      (__attribute__((address_space(3))) unsigned int*)l, 16, 0, 0);
}

__global__ void cvt_bf16(const float* __restrict__ src, u16* __restrict__ dst, int n4) {
  int i = blockIdx.x * blockDim.x + threadIdx.x;
  if (i >= n4) return;
  float4 v = ((const float4*)src)[i];
  ushort4 o;
  o.x = f2bf(v.x); o.y = f2bf(v.y); o.z = f2bf(v.z); o.w = f2bf(v.w);
  ((ushort4*)dst)[i] = o;
}

// C[m,n] = (sum_k A[m,k]*B[n,k] + bias[n]) * scale
// A: [M x K] bf16 row-major, B: [N x K] bf16 row-major (the W matrix, y = x W^T)
// mode 0: out[((b*NH+h)*S + s)*DH + d]   (Q,K -> [B,H,S,Dh] bf16)
// mode 1: out[((b*NH+h)*DH + d)*S + s]   (V   -> [B,H,Dh,S] bf16, transposed)
// mode 2: outf[m*EMB + n]                (final output, fp32 row-major)
__global__ __launch_bounds__(256) void gemm_bt(
    const u16* __restrict__ A, const u16* __restrict__ B,
    const float* __restrict__ bias, u16* __restrict__ out,
    float* __restrict__ outf, int K, float scale, int mode) {
  __shared__ u16 a_sm[128 * 64];
  __shared__ u16 b_sm[128 * 64];
  const int tid = threadIdx.x;
  const int lane = tid & 63, wv = tid >> 6;
  const int l16 = lane & 15, quad = lane >> 4;
  const int m0 = blockIdx.y * 128, n0 = blockIdx.x * 128;
  const int wrow = (wv >> 1) * 64, wcol = (wv & 1) * 64;
  const f32x4 fzero = {0.f, 0.f, 0.f, 0.f};

  f32x4 acc[4][4];
#pragma unroll
  for (int i = 0; i < 4; i++)
#pragma unroll
    for (int j = 0; j < 4; j++) acc[i][j] = fzero;

  const int srow = lane >> 3;        // 0..7 (row within 8-row chunk)
  const int scol = (lane & 7) * 8;   // element offset (8 bf16 = 16B)

  for (int k0 = 0; k0 < K; k0 += 64) {
#pragma unroll
    for (int i = 0; i < 4; i++) {
      int rr = (wv * 4 + i) * 8 + srow;
      int ldso = ((wv * 4 + i) * 64 + lane) * 8;
      gload16(&A[(size_t)(m0 + rr) * K + k0 + scol], &a_sm[ldso]);
      gload16(&B[(size_t)(n0 + rr) * K + k0 + scol], &b_sm[ldso]);
    }
    __syncthreads();
#pragma unroll
    for (int ks = 0; ks < 2; ks++) {
      bf16x8 af[4], bff[4];
#pragma unroll
      for (int t = 0; t < 4; t++) {
        af[t]  = *(const bf16x8*)&a_sm[(wrow + t * 16 + l16) * 64 + ks * 32 + quad * 8];
        bff[t] = *(const bf16x8*)&b_sm[(wcol + t * 16 + l16) * 64 + ks * 32 + quad * 8];
      }
#pragma unroll
      for (int mt = 0; mt < 4; mt++)
#pragma unroll
        for (int nt = 0; nt < 4; nt++)
          acc[mt][nt] = __builtin_amdgcn_mfma_f32_16x16x32_bf16(af[mt], bff[nt], acc[mt][nt], 0, 0, 0);
    }
    __syncthreads();
  }

#pragma unroll
  for (int nt = 0; nt < 4; nt++) {
    const int n = n0 + wcol + nt * 16 + l16;
    const float bv = bias[n];
#pragma unroll
    for (int mt = 0; mt < 4; mt++) {
      const int mb = m0 + wrow + mt * 16 + quad * 4;   // C/D row = quad*4 + reg
      if (mode == 0) {
#pragma unroll
        for (int r = 0; r < 4; r++) {
          int m = mb + r;
          int b = m >> 11, s = m & (S_LEN - 1);
          int h = n >> 6, d = n & 63;
          out[((size_t)(b * NH + h) * S_LEN + s) * DH + d] = f2bf((acc[mt][nt][r] + bv) * scale);
        }
      } else if (mode == 1) {
        int b = mb >> 11, s = mb & (S_LEN - 1);
        int h = n >> 6, d = n & 63;
        ushort4 o;
        o.x = f2bf((acc[mt][nt][0] + bv) * scale);
        o.y = f2bf((acc[mt][nt][1] + bv) * scale);
        o.z = f2bf((acc[mt][nt][2] + bv) * scale);
        o.w = f2bf((acc[mt][nt][3] + bv) * scale);
        *(ushort4*)&out[((size_t)(b * NH + h) * DH + d) * S_LEN + s] = o;
      } else {
#pragma unroll
        for (int r = 0; r < 4; r++) {
          int m = mb + r;
          outf[(size_t)m * EMB + n] = acc[mt][nt][r] + bv;
        }
      }
    }
  }
}

// Pass A: invl[bh, q] = 1 / sum_k exp(Qs . K)   (Q pre-scaled by 1/8)
__global__ __launch_bounds__(256) void attn_pass_a(
    const u16* __restrict__ Qb, const u16* __restrict__ Kb, float* __restrict__ invl) {
  __shared__ u16 q_sm[128 * 64];
  __shared__ u16 k_sm[128 * 64];
  const int tid = threadIdx.x;
  const int lane = tid & 63, wv = tid >> 6;
  const int l16 = lane & 15, quad = lane >> 4;
  const int bh = blockIdx.y, q0 = blockIdx.x * 128;
  const u16* Qp = Qb + (size_t)bh * S_LEN * DH;
  const u16* Kp = Kb + (size_t)bh * S_LEN * DH;

#pragma unroll
  for (int i = 0; i < 4; i++) {
    int off = ((wv * 4 + i) * 64 + lane) * 8;   // tile is contiguous 16KB in global
    gload16(Qp + (size_t)q0 * DH + off, &q_sm[off]);
  }
  __syncthreads();

  bf16x8 aq[2][2];   // wave owns rows wv*32 .. wv*32+31, resident
#pragma unroll
  for (int mt = 0; mt < 2; mt++)
#pragma unroll
    for (int ks = 0; ks < 2; ks++)
      aq[mt][ks] = *(const bf16x8*)&q_sm[(wv * 32 + mt * 16 + l16) * 64 + ks * 32 + quad * 8];

  float racc[8];
#pragma unroll
  for (int i = 0; i < 8; i++) racc[i] = 0.f;
  const f32x4 fzero = {0.f, 0.f, 0.f, 0.f};

  for (int kt0 = 0; kt0 < S_LEN; kt0 += 128) {
#pragma unroll
    for (int i = 0; i < 4; i++) {
      int off = ((wv * 4 + i) * 64 + lane) * 8;
      gload16(Kp + (size_t)kt0 * DH + off, &k_sm[off]);
    }
    __syncthreads();
#pragma unroll
    for (int nt = 0; nt < 8; nt++) {
      bf16x8 bk0 = *(const bf16x8*)&k_sm[(nt * 16 + l16) * 64 + quad * 8];
      bf16x8 bk1 = *(const bf16x8*)&k_sm[(nt * 16 + l16) * 64 + 32 + quad * 8];
#pragma unroll
      for (int mt = 0; mt < 2; mt++) {
        f32x4 c = fzero;
        c = __builtin_amdgcn_mfma_f32_16x16x32_bf16(aq[mt][0], bk0, c, 0, 0, 0);
        c = __builtin_amdgcn_mfma_f32_16x16x32_bf16(aq[mt][1], bk1, c, 0, 0, 0);
#pragma unroll
        for (int r = 0; r < 4; r++) racc[mt * 4 + r] += __expf(c[r]);
      }
    }
    __syncthreads();
  }
  // reduce across the 16 col-lanes of each quad (rows live on quad*4+r)
#pragma unroll
  for (int i = 0; i < 8; i++) {
    racc[i] += __shfl_xor(racc[i], 1);
    racc[i] += __shfl_xor(racc[i], 2);
    racc[i] += __shfl_xor(racc[i], 4);
    racc[i] += __shfl_xor(racc[i], 8);
  }
  if (l16 == 0) {
#pragma unroll
    for (int mt = 0; mt < 2; mt++)
#pragma unroll
      for (int r = 0; r < 4; r++)
        invl[(size_t)bh * S_LEN + q0 + wv * 32 + mt * 16 + quad * 4 + r] = 1.0f / racc[mt * 4 + r];
  }
}

// Pass B: w = exp(Qs.K)*invl -> fp32 attn_weights (direct store) + attn_out = w @ V (bf16)
__global__ __launch_bounds__(256) void attn_pass_b(
    const u16* __restrict__ Qb, const u16* __restrict__ Kb,
    const u16* __restrict__ Vt, const float* __restrict__ invl,
    float* __restrict__ wout, u16* __restrict__ aout) {
  __shared__ u16 k_sm[128 * 64];
  __shared__ u16 vt_sm[64 * 128];
  __shared__ u16 p_sm[128 * 128];
  __shared__ float il_sm[128];
  const int tid = threadIdx.x;
  const int lane = tid & 63, wv = tid >> 6;
  const int l16 = lane & 15, quad = lane >> 4;
  const int bh = blockIdx.y, q0 = blockIdx.x * 128;
  const u16* Qp = Qb + (size_t)bh * S_LEN * DH;
  const u16* Kp = Kb + (size_t)bh * S_LEN * DH;
  const u16* Vp = Vt + (size_t)bh * DH * S_LEN;
  const f32x4 fzero = {0.f, 0.f, 0.f, 0.f};

  // stage Q through k_sm, pull frags resident
#pragma unroll
  for (int i = 0; i < 4; i++) {
    int off = ((wv * 4 + i) * 64 + lane) * 8;
    gload16(Qp + (size_t)q0 * DH + off, &k_sm[off]);
  }
  if (tid < 128) il_sm[tid] = invl[(size_t)bh * S_LEN + q0 + tid];
  __syncthreads();
  bf16x8 aq[2][2];
#pragma unroll
  for (int mt = 0; mt < 2; mt++)
#pragma unroll
    for (int ks = 0; ks < 2; ks++)
      aq[mt][ks] = *(const bf16x8*)&k_sm[(wv * 32 + mt * 16 + l16) * 64 + ks * 32 + quad * 8];
  float il[2][4];
#pragma unroll
  for (int mt = 0; mt < 2; mt++)
#pragma unroll
    for (int r = 0; r < 4; r++)
      il[mt][r] = il_sm[wv * 32 + mt * 16 + quad * 4 + r];
  __syncthreads();   // k_sm gets overwritten below

  f32x4 oacc[8];     // O^T[d][q]: wave owns d rows wv*16..+15, all 128 q
#pragma unroll
  for (int i = 0; i < 8; i++) oacc[i] = fzero;

  const size_t rowbase = ((size_t)bh * S_LEN + q0) * S_LEN;

  for (int kt0 = 0; kt0 < S_LEN; kt0 += 128) {
#pragma unroll
    for (int i = 0; i < 4; i++) {
      int off = ((wv * 4 + i) * 64 + lane) * 8;
      gload16(Kp + (size_t)kt0 * DH + off, &k_sm[off]);
      gload16(Vp + (size_t)((wv * 4 + i) * 4 + quad) * S_LEN + kt0 + l16 * 8, &vt_sm[off]);
    }
    __syncthreads();

    // scores -> exp -> normalized w: fp32 direct to global, bf16 into p_sm
#pragma unroll
    for (int nt = 0; nt < 8; nt++) {
      bf16x8 bk0 = *(const bf16x8*)&k_sm[(nt * 16 + l16) * 64 + quad * 8];
      bf16x8 bk1 = *(const bf16x8*)&k_sm[(nt * 16 + l16) * 64 + 32 + quad * 8];
#pragma unroll
      for (int mt = 0; mt < 2; mt++) {
        f32x4 c = fzero;
        c = __builtin_amdgcn_mfma_f32_16x16x32_bf16(aq[mt][0], bk0, c, 0, 0, 0);
        c = __builtin_amdgcn_mfma_f32_16x16x32_bf16(aq[mt][1], bk1, c, 0, 0, 0);
#pragma unroll
        for (int r = 0; r < 4; r++) {
          float w = __expf(c[r]) * il[mt][r];
          int qlocal = wv * 32 + mt * 16 + quad * 4 + r;
          wout[rowbase + (size_t)qlocal * S_LEN + kt0 + nt * 16 + l16] = w;
          p_sm[qlocal * 128 + nt * 16 + l16] = f2bf(w);
        }
      }
    }
    __syncthreads();

    // O^T += Vt . P^T  (gemm_bt: both frags contiguous-k)
    bf16x8 av[4];
#pragma unroll
    for (int ks = 0; ks < 4; ks++)
      av[ks] = *(const bf16x8*)&vt_sm[(wv * 16 + l16) * 128 + ks * 32 + quad * 8];
#pragma unroll
    for (int nt = 0; nt < 8; nt++)
#pragma unroll
      for (int ks = 0; ks < 4; ks++) {
        bf16x8 bp = *(const bf16x8*)&p_sm[(nt * 16 + l16) * 128 + ks * 32 + quad * 8];
        oacc[nt] = __builtin_amdgcn_mfma_f32_16x16x32_bf16(av[ks], bp, oacc[nt], 0, 0, 0);
      }
    __syncthreads();
  }

  // store attn_out [B,S,E] bf16: rows=d (quad*4+r) -> 4 consecutive d, 8B packed
  const int b = bh >> 4, h = bh & 15;
#pragma unroll
  for (int nt = 0; nt < 8; nt++) {
    int s = q0 + nt * 16 + l16;
    int d0 = wv * 16 + quad * 4;
    ushort4 o;
    o.x = f2bf(oacc[nt][0]);
    o.y = f2bf(oacc[nt][1]);
    o.z = f2bf(oacc[nt][2]);
    o.w = f2bf(oacc[nt][3]);
    *(ushort4*)&aout[(size_t)(b * S_LEN + s) * EMB + h * DH + d0] = o;
  }
}

extern "C" void kernel_launch(void* const* d_in, const int* in_sizes, int n_in,
                              void* d_out, int out_size, void* d_ws, size_t ws_size,
                              hipStream_t stream) {
  const float* q_f  = (const float*)d_in[0];
  const float* k_f  = (const float*)d_in[1];
  const float* v_f  = (const float*)d_in[2];
  const float* qw_f = (const float*)d_in[3];
  const float* qb_f = (const float*)d_in[4];
  const float* kw_f = (const float*)d_in[5];
  const float* kb_f = (const float*)d_in[6];
  const float* vw_f = (const float*)d_in[7];
  const float* vb_f = (const float*)d_in[8];
  const float* ow_f = (const float*)d_in[9];
  const float* ob_f = (const float*)d_in[10];

  uint8_t* wsb = (uint8_t*)d_ws;
  u16*   qb   = (u16*)(wsb + (size_t)(0u  << 20));  // [B,H,S,Dh] bf16, 8 MiB
  u16*   kb   = (u16*)(wsb + (size_t)(8u  << 20));  // [B,H,S,Dh]
  u16*   vt   = (u16*)(wsb + (size_t)(16u << 20));  // [B,H,Dh,S]
  u16*   xq   = (u16*)(wsb + (size_t)(24u << 20));  // activations bf16 [4096,1024]
  u16*   xk   = (u16*)(wsb + (size_t)(32u << 20));
  u16*   xv   = (u16*)(wsb + (size_t)(40u << 20));
  u16*   wq   = (u16*)(wsb + (size_t)(48u << 20));  // weights bf16 [1024,1024], 2 MiB
  u16*   wk   = (u16*)(wsb + (size_t)(50u << 20));
  u16*   wvw  = (u16*)(wsb + (size_t)(52u << 20));
  u16*   wo   = (u16*)(wsb + (size_t)(54u << 20));
  float* invl = (float*)(wsb + (size_t)(56u << 20)); // [32,2048] fp32, 256 KiB
  u16*   ao   = (u16*)(wsb + (size_t)(57u << 20));  // attn_out bf16 [4096,1024], 8 MiB
  // total 65 MiB of workspace

  const int NA4 = (2 * S_LEN * EMB) / 4;   // 1,048,576
  const int NW4 = (EMB * EMB) / 4;         //   262,144
  cvt_bf16<<<NA4 / 256, 256, 0, stream>>>(q_f, xq, NA4);
  cvt_bf16<<<NA4 / 256, 256, 0, stream>>>(k_f, xk, NA4);
  cvt_bf16<<<NA4 / 256, 256, 0, stream>>>(v_f, xv, NA4);
  cvt_bf16<<<NW4 / 256, 256, 0, stream>>>(qw_f, wq, NW4);
  cvt_bf16<<<NW4 / 256, 256, 0, stream>>>(kw_f, wk, NW4);
  cvt_bf16<<<NW4 / 256, 256, 0, stream>>>(vw_f, wvw, NW4);
  cvt_bf16<<<NW4 / 256, 256, 0, stream>>>(ow_f, wo, NW4);

  dim3 gp(8, 32);   // N/128, M/128
  gemm_bt<<<gp, 256, 0, stream>>>(xq, wq, qb_f, qb, nullptr, EMB, 0.125f, 0);  // Q pre-scaled 1/8
  gemm_bt<<<gp, 256, 0, stream>>>(xk, wk, kb_f, kb, nullptr, EMB, 1.0f, 0);
  gemm_bt<<<gp, 256, 0, stream>>>(xv, wvw, vb_f, vt, nullptr, EMB, 1.0f, 1);

  dim3 ga(16, 32);  // S/128 q-tiles, B*H
  attn_pass_a<<<ga, 256, 0, stream>>>(qb, kb, invl);

  float* outp = (float*)d_out;
  attn_pass_b<<<ga, 256, 0, stream>>>(qb, kb, vt, invl, outp + (size_t)2 * S_LEN * EMB, ao);

  gemm_bt<<<gp, 256, 0, stream>>>(ao, wo, ob_f, nullptr, outp, EMB, 1.0f, 2);
}